// Round 6
// baseline (1762.213 us; speedup 1.0000x reference)
//
#include <hip/hip_runtime.h>
#include <stdint.h>

#define BATCH 64
#define TT    150
#define INSZ  120
#define HID   1024
#define OUTN  35
#define NBR   8
#define TPAD  160      // padded T (u64 masks), keeps chunk starts 64B-aligned
#define CH    8        // timesteps per chunk (19 chunks, last has 6 valid)
#define NCHUNK 19

// Constant-address-space loads with a wave-uniform address scalarize to
// s_load (straight into SGPRs), with compiler-managed waits.
typedef unsigned long long u64x8 __attribute__((ext_vector_type(8)));
typedef __attribute__((address_space(4))) const u64x8 cu64x8;

// EXEC-masked accumulate: for each timestep k, set exec to the 64-bit spike
// mask (bit=lane=batch) and add the wave-uniform weight to that step's
// accumulator. Replaces cndmask+add (2 VALU) with s_mov(SALU, hidden on the
// scalar pipe) + add (1 VALU): per-j VALU cycles nearly halve, which is the
// binding resource (busy-time was invariant at ~465us across r0-r5 variants;
// wall tracks VALU instruction count). Bit-exact: a += 0.0f == a except for
// a==-0.0, and accumulators can never be -0.0 (start at +0, RNE gives +0 for
// any exact-zero sum of nonzeros). Exec is saved/restored inside the block.
#define EXEC_ACC8(wv, m, a)                                                  \
    do {                                                                     \
        uint64_t xsv_;                                                       \
        asm("s_mov_b64 %[xsv], exec\n\t"                                     \
            "s_mov_b64 exec, %[xm0]\n\t"                                     \
            "v_add_f32 %[xa0], %[xa0], %[xwv]\n\t"                           \
            "s_mov_b64 exec, %[xm1]\n\t"                                     \
            "v_add_f32 %[xa1], %[xa1], %[xwv]\n\t"                           \
            "s_mov_b64 exec, %[xm2]\n\t"                                     \
            "v_add_f32 %[xa2], %[xa2], %[xwv]\n\t"                           \
            "s_mov_b64 exec, %[xm3]\n\t"                                     \
            "v_add_f32 %[xa3], %[xa3], %[xwv]\n\t"                           \
            "s_mov_b64 exec, %[xm4]\n\t"                                     \
            "v_add_f32 %[xa4], %[xa4], %[xwv]\n\t"                           \
            "s_mov_b64 exec, %[xm5]\n\t"                                     \
            "v_add_f32 %[xa5], %[xa5], %[xwv]\n\t"                           \
            "s_mov_b64 exec, %[xm6]\n\t"                                     \
            "v_add_f32 %[xa6], %[xa6], %[xwv]\n\t"                           \
            "s_mov_b64 exec, %[xm7]\n\t"                                     \
            "v_add_f32 %[xa7], %[xa7], %[xwv]\n\t"                           \
            "s_mov_b64 exec, %[xsv]"                                         \
            : [xa0] "+v"(a[0]), [xa1] "+v"(a[1]), [xa2] "+v"(a[2]),          \
              [xa3] "+v"(a[3]), [xa4] "+v"(a[4]), [xa5] "+v"(a[5]),          \
              [xa6] "+v"(a[6]), [xa7] "+v"(a[7]), [xsv] "=&s"(xsv_)          \
            : [xwv] "v"(wv), [xm0] "s"(m[0]), [xm1] "s"(m[1]),               \
              [xm2] "s"(m[2]), [xm3] "s"(m[3]), [xm4] "s"(m[4]),             \
              [xm5] "s"(m[5]), [xm6] "s"(m[6]), [xm7] "s"(m[7]));            \
    } while (0)

// ---------------- workspace layout (bytes, all 64-aligned) ----------------
#define XT_OFF  0                  // xT  [150][120][64] f32 = 4,608,000
#define S1_OFF  4608000            // s1m [1024][160] u64    = 1,310,720
#define S2_OFF  5918720            // s2m
#define S3_OFF  7229440            // s3m
#define Y_OFF   8540160            // Y   [150][35][64] f32  = 1,344,000
#define ACC_OFF 9884160            // ACC [35][64] f32       = 8,960

// transpose x[b][0][t][i] -> xT[t][i][b], LDS-tiled (both sides coalesced)
__global__ __launch_bounds__(256) void k_tx(const float* __restrict__ x,
                                            float* __restrict__ xT) {
    const int t = blockIdx.x;
    __shared__ float tile[INSZ * 65];
    for (int e = threadIdx.x; e < INSZ * 64; e += 256) {
        const int b = e / INSZ, i = e - b * INSZ;
        tile[i * 65 + b] = x[((size_t)b * TT + t) * INSZ + i];
    }
    __syncthreads();
    for (int e = threadIdx.x; e < INSZ * 64; e += 256) {
        const int i = e >> 6, b = e & 63;
        xT[((size_t)t * INSZ + i) * 64 + b] = tile[i * 65 + b];
    }
}

// One recurrent layer, scans all T steps. grid = HID blocks x 512 threads.
// Block owns 1 neuron (8 branch rows); each wave (64 lanes = 64 batches)
// owns ONE row -> 8192 waves, 4 blocks/CU (LDS-limited, exactly 160KB).
// MODE 0: dense float input from xT. MODE 1: spike masks inm[i*TPAD + t],
// EXEC-masked accumulate (see macro above).
template <int DIN, int NNZ, int MODE>
__global__ __launch_bounds__(512, 8) void k_layer(
    const float* __restrict__ w,            // [HID*NBR, DIN]
    const void* __restrict__ maskp,         // [HID*NBR, DIN] bool (u8 or i32)
    const float* __restrict__ bias,         // [HID*NBR]
    const float* __restrict__ tau_m,        // [HID]
    const float* __restrict__ tau_n,        // [HID*NBR]
    const float* __restrict__ xin,          // MODE0: [T][DIN][64]
    const uint64_t* __restrict__ inm,       // MODE1: [DIN][TPAD]
    uint64_t* __restrict__ outm)            // [HID][TPAD]
{
    const int tid  = threadIdx.x;
    const int lane = tid & 63;
    const int wid  = tid >> 6;              // 0..7 (branch row)
    const int h    = blockIdx.x;
    const int r    = h * NBR + wid;         // this wave's row

    __shared__ uint2 ent[NBR * NNZ];        // (w bits, idx) per row
    __shared__ float red[2][NBR * CH * 64]; // double-buffered partial sums

    inm = (const uint64_t*)__builtin_assume_aligned(inm, 64);

    // ---- gather masked weights into LDS (ballot compaction) ----
    const unsigned char* m8  = (const unsigned char*)maskp;
    const int*           m32 = (const int*)maskp;
    {
        const int base = wid * NNZ;
        int cnt = 0;
        for (int c = 0; c * 64 < DIN; ++c) {
            const int i = c * 64 + lane;
            int   mv = 0;
            float wv = 0.f;
            if (i < DIN) {
                mv = m8[(size_t)r * DIN + i];
                wv = w[(size_t)r * DIN + i];
            }
            const unsigned long long bal = __ballot(mv != 0);
            const int pos = __popcll(bal & ((1ull << lane) - 1ull));
            if (mv && cnt + pos < NNZ)
                ent[base + cnt + pos] = make_uint2(__float_as_uint(wv), (unsigned)i);
            cnt += __popcll(bal);
        }
        if (cnt != NNZ) {   // masks are int32 after all
            cnt = 0;
            for (int c = 0; c * 64 < DIN; ++c) {
                const int i = c * 64 + lane;
                int   mv = 0;
                float wv = 0.f;
                if (i < DIN) {
                    mv = m32[(size_t)r * DIN + i];
                    wv = w[(size_t)r * DIN + i];
                }
                const unsigned long long bal = __ballot(mv != 0);
                const int pos = __popcll(bal & ((1ull << lane) - 1ull));
                if (mv) ent[base + cnt + pos] =
                            make_uint2(__float_as_uint(wv), (unsigned)i);
                cnt += __popcll(bal);
            }
        }
    }
    __syncthreads();

    const float be = 1.f / (1.f + expf(-tau_n[r]));
    const float om = 1.f - be;
    const float bb = bias[r];
    const float al  = 1.f / (1.f + expf(-tau_m[h]));
    const float oma = 1.f - al;

    float d = 0.f, mem = 0.f, spkprev = 0.f;
    const int base = wid * NNZ;

    for (int tc = 0; tc < NCHUNK; ++tc) {
        const int t0  = tc * CH;
        const int buf = tc & 1;
        float a[CH];
#pragma unroll
        for (int k = 0; k < CH; ++k) a[k] = 0.f;

        if constexpr (MODE == 1) {
#pragma unroll 4
            for (int j = 0; j < NNZ; ++j) {
                const uint2 e  = ent[base + j];
                const int   ix = __builtin_amdgcn_readfirstlane((int)e.y);
                const float wv = __uint_as_float(e.x);
                const u64x8 m = *(const cu64x8*)(inm + (size_t)ix * TPAD + t0);
                EXEC_ACC8(wv, m, a);
            }
        } else {
            const float* xb = xin + (size_t)t0 * DIN * 64;
#pragma unroll 3
            for (int j = 0; j < NNZ; ++j) {
                const uint2 e  = ent[base + j];
                const int   ix = __builtin_amdgcn_readfirstlane((int)e.y);
                const float wv = __uint_as_float(e.x);
#pragma unroll
                for (int k = 0; k < CH; ++k)
                    a[k] += wv * xb[((size_t)k * DIN + ix) * 64 + lane];
            }
        }

        // branch decay (sequential within chunk), stash per-row d
#pragma unroll
        for (int k = 0; k < CH; ++k) {
            d = be * d + om * (a[k] + bb);
            red[buf][(wid * CH + k) * 64 + lane] = d;
        }
        // one barrier per chunk: waves 1..7 run chunk tc+1 into buf^1 while
        // wave 0 reduces buf; buf is rewritten only after the NEXT barrier.
        __syncthreads();

        if (wid == 0) {
#pragma unroll
            for (int k = 0; k < CH; ++k) {
                // EXACT old pair order: ((d0+d1)+(d2+d3))+(d4+d5))+(d6+d7)
                const float r0 = red[buf][(0 * CH + k) * 64 + lane];
                const float r1 = red[buf][(1 * CH + k) * 64 + lane];
                const float r2 = red[buf][(2 * CH + k) * 64 + lane];
                const float r3 = red[buf][(3 * CH + k) * 64 + lane];
                const float r4 = red[buf][(4 * CH + k) * 64 + lane];
                const float r5 = red[buf][(5 * CH + k) * 64 + lane];
                const float r6 = red[buf][(6 * CH + k) * 64 + lane];
                const float r7 = red[buf][(7 * CH + k) * 64 + lane];
                const float p01 = r0 + r1, p23 = r2 + r3;
                const float p45 = r4 + r5, p67 = r6 + r7;
                const float l = ((p01 + p23) + p45) + p67;
                if (t0 + k < TT) {
                    mem = al * mem + oma * l - spkprev;   // VTH = 1.0
                    spkprev = (mem > 1.0f) ? 1.f : 0.f;
                    const unsigned long long bal = __ballot(mem > 1.0f);
                    if (lane == 0) outm[(size_t)h * TPAD + (t0 + k)] = bal;
                }
            }
        }
    }
}

// Y[t][o][b] = wr[o] . s3(t,:,b); 4 waves split the i range (reorder safe:
// readout is linear, no thresholds downstream). wid goes through
// readfirstlane so LLVM knows the mask addresses are uniform; masks are read
// through AS(4) pointers -> scalar s_load; same EXEC-masked accumulate.
__global__ __launch_bounds__(256) void k_ry(const float* __restrict__ wr,
                                            const uint64_t* __restrict__ s3m,
                                            float* __restrict__ Y) {
    const int lane  = threadIdx.x & 63;
    const int wid   = __builtin_amdgcn_readfirstlane(threadIdx.x >> 6); // 0..3
    const int o  = blockIdx.x / NCHUNK;
    const int t0 = (blockIdx.x % NCHUNK) * CH;
    s3m = (const uint64_t*)__builtin_assume_aligned(s3m, 64);
    const float* wrow = wr + (size_t)o * HID;
    __shared__ float red[4 * CH * 64];
    float acc[CH];
#pragma unroll
    for (int k = 0; k < CH; ++k) acc[k] = 0.f;
#pragma unroll 4
    for (int ii = 0; ii < HID / 4; ++ii) {
        const int i = wid * (HID / 4) + ii;
        const float wv = wrow[i];
        const u64x8 m = *(const cu64x8*)(s3m + (size_t)i * TPAD + t0);
        EXEC_ACC8(wv, m, acc);
    }
#pragma unroll
    for (int k = 0; k < CH; ++k)
        red[(wid * CH + k) * 64 + lane] = acc[k];
    __syncthreads();
    if (wid == 0) {
#pragma unroll
        for (int k = 0; k < CH; ++k) {
            if (t0 + k >= TT) break;
            const float v = ((red[(0 * CH + k) * 64 + lane]
                            + red[(1 * CH + k) * 64 + lane])
                            + red[(2 * CH + k) * 64 + lane])
                            + red[(3 * CH + k) * 64 + lane];
            Y[((size_t)(t0 + k) * OUTN + o) * 64 + lane] = v;
        }
    }
}

// acc[o][b] = sum_t (Y + br[o]) * (1 - ar^(150-t))   (closed-form mr scan)
__global__ void k_racc(const float* __restrict__ Y,
                       const float* __restrict__ br,
                       const float* __restrict__ tau_mr,
                       float* __restrict__ ACC) {
    const int o = blockIdx.x, lane = threadIdx.x;
    const float ar  = 1.f / (1.f + expf(-tau_mr[o]));
    const float bro = br[o];
    float acc = 0.f, q = ar;
    for (int t = TT - 1; t >= 0; --t) {
        const float y = Y[((size_t)t * OUTN + o) * 64 + lane] + bro;
        acc += y * (1.f - q);
        q *= ar;
    }
    ACC[o * 64 + lane] = acc;
}

__global__ void k_smax(const float* __restrict__ ACC, float* __restrict__ out) {
    const int b = threadIdx.x;   // 64 threads
    float v[OUTN];
    float mx = -3.4e38f;
    for (int o = 0; o < OUTN; ++o) {
        v[o] = ACC[o * 64 + b] / (float)TT;
        mx = fmaxf(mx, v[o]);
    }
    float sum = 0.f;
    for (int o = 0; o < OUTN; ++o) sum += expf(v[o] - mx);
    const float lse = mx + logf(sum);
    for (int o = 0; o < OUTN; ++o) out[b * OUTN + o] = v[o] - lse;
}

extern "C" void kernel_launch(void* const* d_in, const int* in_sizes, int n_in,
                              void* d_out, int out_size, void* d_ws,
                              size_t ws_size, hipStream_t stream) {
    (void)in_sizes; (void)n_in; (void)out_size; (void)ws_size;
    const float* x   = (const float*)d_in[0];
    const float* w1  = (const float*)d_in[1];
    const float* b1  = (const float*)d_in[2];
    const float* tm1 = (const float*)d_in[3];
    const float* tn1 = (const float*)d_in[4];
    const float* w2  = (const float*)d_in[5];
    const float* b2  = (const float*)d_in[6];
    const float* tm2 = (const float*)d_in[7];
    const float* tn2 = (const float*)d_in[8];
    const float* w3  = (const float*)d_in[9];
    const float* b3  = (const float*)d_in[10];
    const float* tm3 = (const float*)d_in[11];
    const float* tn3 = (const float*)d_in[12];
    const float* wr  = (const float*)d_in[13];
    const float* br  = (const float*)d_in[14];
    const float* tmr = (const float*)d_in[15];
    const void*  m1  = d_in[16];
    const void*  m2  = d_in[17];
    const void*  m3  = d_in[18];
    float* out = (float*)d_out;

    char* ws = (char*)d_ws;
    float*    xT  = (float*)(ws + XT_OFF);
    uint64_t* s1m = (uint64_t*)(ws + S1_OFF);
    uint64_t* s2m = (uint64_t*)(ws + S2_OFF);
    uint64_t* s3m = (uint64_t*)(ws + S3_OFF);
    float*    Y   = (float*)(ws + Y_OFF);
    float*    ACC = (float*)(ws + ACC_OFF);

    k_tx<<<TT, 256, 0, stream>>>(x, xT);
    k_layer<INSZ, 15, 0><<<HID, 512, 0, stream>>>(
        w1, m1, b1, tm1, tn1, xT, nullptr, s1m);
    k_layer<HID, 128, 1><<<HID, 512, 0, stream>>>(
        w2, m2, b2, tm2, tn2, nullptr, s1m, s2m);
    k_layer<HID, 128, 1><<<HID, 512, 0, stream>>>(
        w3, m3, b3, tm3, tn3, nullptr, s2m, s3m);
    k_ry<<<OUTN * NCHUNK, 256, 0, stream>>>(wr, s3m, Y);
    k_racc<<<OUTN, 64, 0, stream>>>(Y, br, tmr, ACC);
    k_smax<<<1, 64, 0, stream>>>(ACC, out);
}

// Round 7
// 1711.544 us; speedup vs baseline: 1.0296x; 1.0296x over previous
//
#include <hip/hip_runtime.h>
#include <stdint.h>

#define BATCH 64
#define TT    150
#define INSZ  120
#define HID   1024
#define OUTN  35
#define NBR   8
#define TPAD  160      // padded T (u64 masks), keeps chunk starts 64B-aligned
#define CH    8        // timesteps per chunk (19 chunks, last has 6 valid)
#define NCHUNK 19
#define NNZC  128      // nnz per row for the two recurrent (HID-input) layers

// Constant-address-space loads with a wave-uniform address scalarize to
// s_load (straight into SGPRs), with compiler-managed waits.
typedef unsigned long long u64x8 __attribute__((ext_vector_type(8)));
typedef int   i32x8 __attribute__((ext_vector_type(8)));
typedef float f32x8 __attribute__((ext_vector_type(8)));
typedef __attribute__((address_space(4))) const u64x8 cu64x8;
typedef __attribute__((address_space(4))) const i32x8 ci32x8;
typedef __attribute__((address_space(4))) const f32x8 cf32x8;

// ---------------- workspace layout (bytes, all 64-aligned) ----------------
#define XT_OFF  0                  // xT  [150][120][64] f32 = 4,608,000
#define S1_OFF  4608000            // s1m [1024][160] u64    = 1,310,720
#define S2_OFF  5918720            // s2m
#define S3_OFF  7229440            // s3m
#define Y_OFF   8540160            // Y   [150][35][64] f32  = 1,344,000
#define ACC_OFF 9884160            // ACC [35][64] f32       = 8,960
#define WC2_OFF 9893120            // wcomp2 [8192][128] f32 = 4,194,304
#define IC2_OFF 14087424           // icomp2 [8192][128] i32 = 4,194,304
#define WC3_OFF 18281728           // wcomp3
#define IC3_OFF 22476032           // icomp3  (end 26,670,336)

// transpose x[b][0][t][i] -> xT[t][i][b], LDS-tiled (both sides coalesced)
__global__ __launch_bounds__(256) void k_tx(const float* __restrict__ x,
                                            float* __restrict__ xT) {
    const int t = blockIdx.x;
    __shared__ float tile[INSZ * 65];
    for (int e = threadIdx.x; e < INSZ * 64; e += 256) {
        const int b = e / INSZ, i = e - b * INSZ;
        tile[i * 65 + b] = x[((size_t)b * TT + t) * INSZ + i];
    }
    __syncthreads();
    for (int e = threadIdx.x; e < INSZ * 64; e += 256) {
        const int i = e >> 6, b = e & 63;
        xT[((size_t)t * INSZ + i) * 64 + b] = tile[i * 65 + b];
    }
}

// One-off row compaction into GLOBAL (w, idx) arrays, ascending index order —
// identical order to the old in-kernel ballot compaction (bit-exact sums).
// One wave per row; grid = HID blocks x 512 threads (8 rows/block).
__global__ __launch_bounds__(512) void k_cmp(const float* __restrict__ w,
                                             const void* __restrict__ maskp,
                                             float* __restrict__ wcomp,
                                             int* __restrict__ icomp) {
    const int lane = threadIdx.x & 63;
    const int wid  = threadIdx.x >> 6;
    const int r    = blockIdx.x * NBR + wid;
    const unsigned char* m8  = (const unsigned char*)maskp;
    const int*           m32 = (const int*)maskp;
    float* wout = wcomp + (size_t)r * NNZC;
    int*   iout = icomp + (size_t)r * NNZC;
    int cnt = 0;
    for (int c = 0; c * 64 < HID; ++c) {
        const int i = c * 64 + lane;
        const int   mv = m8[(size_t)r * HID + i];
        const float wv = w[(size_t)r * HID + i];
        const unsigned long long bal = __ballot(mv != 0);
        const int pos = __popcll(bal & ((1ull << lane) - 1ull));
        if (mv && cnt + pos < NNZC) { wout[cnt + pos] = wv; iout[cnt + pos] = i; }
        cnt += __popcll(bal);
    }
    if (cnt != NNZC) {   // masks are int32 after all
        cnt = 0;
        for (int c = 0; c * 64 < HID; ++c) {
            const int i = c * 64 + lane;
            const int   mv = m32[(size_t)r * HID + i];
            const float wv = w[(size_t)r * HID + i];
            const unsigned long long bal = __ballot(mv != 0);
            const int pos = __popcll(bal & ((1ull << lane) - 1ull));
            if (mv) { wout[cnt + pos] = wv; iout[cnt + pos] = i; }
            cnt += __popcll(bal);
        }
    }
}

// One recurrent layer, scans all T steps. grid = HID blocks x 512 threads.
// Block owns 1 neuron (8 branch rows); each wave (64 lanes = 64 batches)
// owns ONE row. MODE 0: dense float input from xT, LDS-compacted entries.
// MODE 1: spike masks inm[i*TPAD + t]; (w, idx) pre-compacted in GLOBAL and
// fetched with pure-SMEM batches: per 8-j group one s_load_dwordx8 of idx,
// one of weights, and 8 mask s_load_dwordx16 — no per-j ds_read, no
// readfirstlane, no DS/SMEM lgkm mixing. One conservative drain per GROUP
// (8 j) instead of per j: the wall-vs-VALUBusy gap (165us/layer) was this
// serial ds->rfl->s_load chain's exposed latency.
template <int DIN, int NNZ, int MODE>
__global__ __launch_bounds__(512, 8) void k_layer(
    const float* __restrict__ w,            // [HID*NBR, DIN]
    const void* __restrict__ maskp,         // [HID*NBR, DIN] bool (u8 or i32)
    const float* __restrict__ bias,         // [HID*NBR]
    const float* __restrict__ tau_m,        // [HID]
    const float* __restrict__ tau_n,        // [HID*NBR]
    const float* __restrict__ xin,          // MODE0: [T][DIN][64]
    const uint64_t* __restrict__ inm,       // MODE1: [DIN][TPAD]
    const float* __restrict__ wcomp,        // MODE1: [HID*NBR][NNZ]
    const int* __restrict__ icomp,          // MODE1: [HID*NBR][NNZ]
    uint64_t* __restrict__ outm)            // [HID][TPAD]
{
    const int tid  = threadIdx.x;
    const int lane = tid & 63;
    const int wid  = __builtin_amdgcn_readfirstlane(tid >> 6); // 0..7, uniform
    const int h    = blockIdx.x;
    const int r    = h * NBR + wid;         // this wave's row

    __shared__ uint2 ent[(MODE == 0) ? (NBR * NNZ) : 1]; // MODE0 only
    __shared__ float red[2][NBR * CH * 64]; // double-buffered partial sums

    inm = (const uint64_t*)__builtin_assume_aligned(inm, 64);

    if constexpr (MODE == 0) {
        // ---- gather masked weights into LDS (ballot compaction) ----
        const unsigned char* m8  = (const unsigned char*)maskp;
        const int*           m32 = (const int*)maskp;
        const int base = wid * NNZ;
        int cnt = 0;
        for (int c = 0; c * 64 < DIN; ++c) {
            const int i = c * 64 + lane;
            int   mv = 0;
            float wv = 0.f;
            if (i < DIN) {
                mv = m8[(size_t)r * DIN + i];
                wv = w[(size_t)r * DIN + i];
            }
            const unsigned long long bal = __ballot(mv != 0);
            const int pos = __popcll(bal & ((1ull << lane) - 1ull));
            if (mv && cnt + pos < NNZ)
                ent[base + cnt + pos] = make_uint2(__float_as_uint(wv), (unsigned)i);
            cnt += __popcll(bal);
        }
        if (cnt != NNZ) {   // masks are int32 after all
            cnt = 0;
            for (int c = 0; c * 64 < DIN; ++c) {
                const int i = c * 64 + lane;
                int   mv = 0;
                float wv = 0.f;
                if (i < DIN) {
                    mv = m32[(size_t)r * DIN + i];
                    wv = w[(size_t)r * DIN + i];
                }
                const unsigned long long bal = __ballot(mv != 0);
                const int pos = __popcll(bal & ((1ull << lane) - 1ull));
                if (mv) ent[base + cnt + pos] =
                            make_uint2(__float_as_uint(wv), (unsigned)i);
                cnt += __popcll(bal);
            }
        }
        __syncthreads();
    }

    const float be = 1.f / (1.f + expf(-tau_n[r]));
    const float om = 1.f - be;
    const float bb = bias[r];
    const float al  = 1.f / (1.f + expf(-tau_m[h]));
    const float oma = 1.f - al;

    float d = 0.f, mem = 0.f, spkprev = 0.f;

    for (int tc = 0; tc < NCHUNK; ++tc) {
        const int t0  = tc * CH;
        const int buf = tc & 1;
        float a[CH];
#pragma unroll
        for (int k = 0; k < CH; ++k) a[k] = 0.f;

        if constexpr (MODE == 1) {
            const float* __restrict__ wcp = wcomp + (size_t)r * NNZ;
            const int*   __restrict__ icp = icomp + (size_t)r * NNZ;
            static_assert(NNZ % 8 == 0, "NNZ multiple of 8");
#pragma unroll 2
            for (int jb = 0; jb < NNZ / 8; ++jb) {
                const i32x8 ix8 = *(const ci32x8*)(icp + jb * 8);
                const f32x8 wv8 = *(const cf32x8*)(wcp + jb * 8);
#pragma unroll
                for (int jj = 0; jj < 8; ++jj) {
                    const u64x8 m =
                        *(const cu64x8*)(inm + (size_t)ix8[jj] * TPAD + t0);
                    const float wv = wv8[jj];
#pragma unroll
                    for (int k = 0; k < CH; ++k) {
                        float s;
                        asm("v_cndmask_b32 %0, 0, %1, %2"
                            : "=v"(s) : "v"(wv), "s"(m[k]));
                        a[k] += s;
                    }
                }
            }
        } else {
            const int base = wid * NNZ;
            const float* xb = xin + (size_t)t0 * DIN * 64;
#pragma unroll 3
            for (int j = 0; j < NNZ; ++j) {
                const uint2 e  = ent[base + j];
                const int   ix = __builtin_amdgcn_readfirstlane((int)e.y);
                const float wv = __uint_as_float(e.x);
#pragma unroll
                for (int k = 0; k < CH; ++k)
                    a[k] += wv * xb[((size_t)k * DIN + ix) * 64 + lane];
            }
        }

        // branch decay (sequential within chunk), stash per-row d
#pragma unroll
        for (int k = 0; k < CH; ++k) {
            d = be * d + om * (a[k] + bb);
            red[buf][(wid * CH + k) * 64 + lane] = d;
        }
        // one barrier per chunk: waves 1..7 run chunk tc+1 into buf^1 while
        // wave 0 reduces buf; buf is rewritten only after the NEXT barrier.
        __syncthreads();

        if (wid == 0) {
#pragma unroll
            for (int k = 0; k < CH; ++k) {
                // EXACT old pair order: ((d0+d1)+(d2+d3))+(d4+d5))+(d6+d7)
                const float r0 = red[buf][(0 * CH + k) * 64 + lane];
                const float r1 = red[buf][(1 * CH + k) * 64 + lane];
                const float r2 = red[buf][(2 * CH + k) * 64 + lane];
                const float r3 = red[buf][(3 * CH + k) * 64 + lane];
                const float r4 = red[buf][(4 * CH + k) * 64 + lane];
                const float r5 = red[buf][(5 * CH + k) * 64 + lane];
                const float r6 = red[buf][(6 * CH + k) * 64 + lane];
                const float r7 = red[buf][(7 * CH + k) * 64 + lane];
                const float p01 = r0 + r1, p23 = r2 + r3;
                const float p45 = r4 + r5, p67 = r6 + r7;
                const float l = ((p01 + p23) + p45) + p67;
                if (t0 + k < TT) {
                    mem = al * mem + oma * l - spkprev;   // VTH = 1.0
                    spkprev = (mem > 1.0f) ? 1.f : 0.f;
                    const unsigned long long bal = __ballot(mem > 1.0f);
                    if (lane == 0) outm[(size_t)h * TPAD + (t0 + k)] = bal;
                }
            }
        }
    }
}

// Y[t][o][b] = wr[o] . s3(t,:,b); 4 waves split the i range (reorder safe:
// readout is linear, no thresholds downstream). wid goes through
// readfirstlane so LLVM knows the mask addresses are uniform; masks are read
// through AS(4) pointers -> scalar s_load, no marshalling.
__global__ __launch_bounds__(256) void k_ry(const float* __restrict__ wr,
                                            const uint64_t* __restrict__ s3m,
                                            float* __restrict__ Y) {
    const int lane  = threadIdx.x & 63;
    const int wid   = __builtin_amdgcn_readfirstlane(threadIdx.x >> 6); // 0..3
    const int o  = blockIdx.x / NCHUNK;
    const int t0 = (blockIdx.x % NCHUNK) * CH;
    s3m = (const uint64_t*)__builtin_assume_aligned(s3m, 64);
    const float* wrow = wr + (size_t)o * HID;
    __shared__ float red[4 * CH * 64];
    float acc[CH];
#pragma unroll
    for (int k = 0; k < CH; ++k) acc[k] = 0.f;
#pragma unroll 4
    for (int ii = 0; ii < HID / 4; ++ii) {
        const int i = wid * (HID / 4) + ii;
        const float wv = wrow[i];
        const u64x8 m = *(const cu64x8*)(s3m + (size_t)i * TPAD + t0);
#pragma unroll
        for (int k = 0; k < CH; ++k) {
            float s;
            asm("v_cndmask_b32 %0, 0, %1, %2" : "=v"(s) : "v"(wv), "s"(m[k]));
            acc[k] += s;
        }
    }
#pragma unroll
    for (int k = 0; k < CH; ++k)
        red[(wid * CH + k) * 64 + lane] = acc[k];
    __syncthreads();
    if (wid == 0) {
#pragma unroll
        for (int k = 0; k < CH; ++k) {
            if (t0 + k >= TT) break;
            const float v = ((red[(0 * CH + k) * 64 + lane]
                            + red[(1 * CH + k) * 64 + lane])
                            + red[(2 * CH + k) * 64 + lane])
                            + red[(3 * CH + k) * 64 + lane];
            Y[((size_t)(t0 + k) * OUTN + o) * 64 + lane] = v;
        }
    }
}

// acc[o][b] = sum_t (Y + br[o]) * (1 - ar^(150-t))   (closed-form mr scan)
__global__ void k_racc(const float* __restrict__ Y,
                       const float* __restrict__ br,
                       const float* __restrict__ tau_mr,
                       float* __restrict__ ACC) {
    const int o = blockIdx.x, lane = threadIdx.x;
    const float ar  = 1.f / (1.f + expf(-tau_mr[o]));
    const float bro = br[o];
    float acc = 0.f, q = ar;
    for (int t = TT - 1; t >= 0; --t) {
        const float y = Y[((size_t)t * OUTN + o) * 64 + lane] + bro;
        acc += y * (1.f - q);
        q *= ar;
    }
    ACC[o * 64 + lane] = acc;
}

__global__ void k_smax(const float* __restrict__ ACC, float* __restrict__ out) {
    const int b = threadIdx.x;   // 64 threads
    float v[OUTN];
    float mx = -3.4e38f;
    for (int o = 0; o < OUTN; ++o) {
        v[o] = ACC[o * 64 + b] / (float)TT;
        mx = fmaxf(mx, v[o]);
    }
    float sum = 0.f;
    for (int o = 0; o < OUTN; ++o) sum += expf(v[o] - mx);
    const float lse = mx + logf(sum);
    for (int o = 0; o < OUTN; ++o) out[b * OUTN + o] = v[o] - lse;
}

extern "C" void kernel_launch(void* const* d_in, const int* in_sizes, int n_in,
                              void* d_out, int out_size, void* d_ws,
                              size_t ws_size, hipStream_t stream) {
    (void)in_sizes; (void)n_in; (void)out_size; (void)ws_size;
    const float* x   = (const float*)d_in[0];
    const float* w1  = (const float*)d_in[1];
    const float* b1  = (const float*)d_in[2];
    const float* tm1 = (const float*)d_in[3];
    const float* tn1 = (const float*)d_in[4];
    const float* w2  = (const float*)d_in[5];
    const float* b2  = (const float*)d_in[6];
    const float* tm2 = (const float*)d_in[7];
    const float* tn2 = (const float*)d_in[8];
    const float* w3  = (const float*)d_in[9];
    const float* b3  = (const float*)d_in[10];
    const float* tm3 = (const float*)d_in[11];
    const float* tn3 = (const float*)d_in[12];
    const float* wr  = (const float*)d_in[13];
    const float* br  = (const float*)d_in[14];
    const float* tmr = (const float*)d_in[15];
    const void*  m1  = d_in[16];
    const void*  m2  = d_in[17];
    const void*  m3  = d_in[18];
    float* out = (float*)d_out;

    char* ws = (char*)d_ws;
    float*    xT  = (float*)(ws + XT_OFF);
    uint64_t* s1m = (uint64_t*)(ws + S1_OFF);
    uint64_t* s2m = (uint64_t*)(ws + S2_OFF);
    uint64_t* s3m = (uint64_t*)(ws + S3_OFF);
    float*    Y   = (float*)(ws + Y_OFF);
    float*    ACC = (float*)(ws + ACC_OFF);
    float*    wc2 = (float*)(ws + WC2_OFF);
    int*      ic2 = (int*)(ws + IC2_OFF);
    float*    wc3 = (float*)(ws + WC3_OFF);
    int*      ic3 = (int*)(ws + IC3_OFF);

    k_tx<<<TT, 256, 0, stream>>>(x, xT);
    k_cmp<<<HID, 512, 0, stream>>>(w2, m2, wc2, ic2);
    k_cmp<<<HID, 512, 0, stream>>>(w3, m3, wc3, ic3);
    k_layer<INSZ, 15, 0><<<HID, 512, 0, stream>>>(
        w1, m1, b1, tm1, tn1, xT, nullptr, nullptr, nullptr, s1m);
    k_layer<HID, NNZC, 1><<<HID, 512, 0, stream>>>(
        w2, m2, b2, tm2, tn2, nullptr, s1m, wc2, ic2, s2m);
    k_layer<HID, NNZC, 1><<<HID, 512, 0, stream>>>(
        w3, m3, b3, tm3, tn3, nullptr, s2m, wc3, ic3, s3m);
    k_ry<<<OUTN * NCHUNK, 256, 0, stream>>>(wr, s3m, Y);
    k_racc<<<OUTN, 64, 0, stream>>>(Y, br, tmr, ACC);
    k_smax<<<1, 64, 0, stream>>>(ACC, out);
}

// Round 9
// 1696.701 us; speedup vs baseline: 1.0386x; 1.0087x over previous
//
#include <hip/hip_runtime.h>
#include <stdint.h>

#define BATCH 64
#define TT    150
#define INSZ  120
#define HID   1024
#define OUTN  35
#define NBR   8
#define TPAD  160      // padded T (u64 masks), keeps chunk starts 64B-aligned
#define CH    8        // timesteps per chunk (19 chunks, last has 6 valid)
#define NCHUNK 19
#define NNZC  128      // nnz per row for the two recurrent (HID-input) layers

// Constant-address-space loads with a wave-uniform address scalarize to
// s_load (straight into SGPRs), with compiler-managed waits.
typedef unsigned long long u64x8 __attribute__((ext_vector_type(8)));
typedef int   i32x8 __attribute__((ext_vector_type(8)));
typedef float f32x8 __attribute__((ext_vector_type(8)));
typedef __attribute__((address_space(4))) const u64x8 cu64x8;
typedef __attribute__((address_space(4))) const i32x8 ci32x8;

// ---------------- workspace layout (bytes, all 64-aligned) ----------------
#define XT_OFF  0                  // xT  [150][120][64] f32 = 4,608,000
#define S1_OFF  4608000            // s1m [1024][160] u64    = 1,310,720
#define S2_OFF  5918720            // s2m
#define S3_OFF  7229440            // s3m
#define Y_OFF   8540160            // Y   [150][35][64] f32  = 1,344,000
#define ACC_OFF 9884160            // ACC [35][64] f32       = 8,960
#define IC2_OFF 9893120            // icomp2 [8192][128] i32 = 4,194,304
#define IC3_OFF 14087424           // icomp3                 (end 18,281,728)

// transpose x[b][0][t][i] -> xT[t][i][b], LDS-tiled (both sides coalesced)
__global__ __launch_bounds__(256) void k_tx(const float* __restrict__ x,
                                            float* __restrict__ xT) {
    const int t = blockIdx.x;
    __shared__ float tile[INSZ * 65];
    for (int e = threadIdx.x; e < INSZ * 64; e += 256) {
        const int b = e / INSZ, i = e - b * INSZ;
        tile[i * 65 + b] = x[((size_t)b * TT + t) * INSZ + i];
    }
    __syncthreads();
    for (int e = threadIdx.x; e < INSZ * 64; e += 256) {
        const int i = e >> 6, b = e & 63;
        xT[((size_t)t * INSZ + i) * 64 + b] = tile[i * 65 + b];
    }
}

// One-off index compaction into GLOBAL, ascending order — identical order to
// the in-kernel ballot compaction (bit-exact j sequence). m8-probe first
// (never over-reads), m32 fallback — same OOB-safe order as the layer gather.
// One wave per row; grid = HID blocks x 512 threads (8 rows/block).
__global__ __launch_bounds__(512) void k_cmp(const void* __restrict__ maskp,
                                             int* __restrict__ icomp) {
    const int lane = threadIdx.x & 63;
    const int wid  = threadIdx.x >> 6;
    const int r    = blockIdx.x * NBR + wid;
    const unsigned char* m8  = (const unsigned char*)maskp;
    const int*           m32 = (const int*)maskp;
    int* iout = icomp + (size_t)r * NNZC;
    int cnt = 0;
    for (int c = 0; c * 64 < HID; ++c) {
        const int i = c * 64 + lane;
        const int mv = m8[(size_t)r * HID + i];
        const unsigned long long bal = __ballot(mv != 0);
        const int pos = __popcll(bal & ((1ull << lane) - 1ull));
        if (mv && cnt + pos < NNZC) iout[cnt + pos] = i;
        cnt += __popcll(bal);
    }
    if (cnt != NNZC) {   // masks are int32 after all
        cnt = 0;
        for (int c = 0; c * 64 < HID; ++c) {
            const int i = c * 64 + lane;
            const int mv = m32[(size_t)r * HID + i];
            const unsigned long long bal = __ballot(mv != 0);
            const int pos = __popcll(bal & ((1ull << lane) - 1ull));
            if (mv && cnt + pos < NNZC) iout[cnt + pos] = i;
            cnt += __popcll(bal);
        }
    }
}

// One recurrent layer, scans all T steps. grid = HID blocks x 512 threads.
// Block owns 1 neuron (8 branch rows); each wave (64 lanes = 64 batches)
// owns ONE row -> 8192 waves, 4 blocks/CU.
// MODE 0: dense float input from xT (r2 structure, unchanged).
// MODE 1: spike masks inm[i*TPAD + t]. 16-VALU/j floor: indices come from
// GLOBAL pre-compaction via s_load (SGPR -> mask address, no readfirstlane
// in the loop); weights come from an LDS ballot-gather read as f32x8
// ds_read_b128 (VGPR -> v_cndmask src, no v_mov). Per j: 8 cndmask + 8 add.
// NOTE: wid MUST go through readfirstlane — LLVM's divergence analysis
// otherwise marks r -> icomp addr -> mask addr divergent and the "s"
// constraint on the mask operand becomes unsatisfiable (r8 compile failure).
template <int DIN, int NNZ, int MODE>
__global__ __launch_bounds__(512, 8) void k_layer(
    const float* __restrict__ w,            // [HID*NBR, DIN]
    const void* __restrict__ maskp,         // [HID*NBR, DIN] bool (u8 or i32)
    const float* __restrict__ bias,         // [HID*NBR]
    const float* __restrict__ tau_m,        // [HID]
    const float* __restrict__ tau_n,        // [HID*NBR]
    const float* __restrict__ xin,          // MODE0: [T][DIN][64]
    const uint64_t* __restrict__ inm,       // MODE1: [DIN][TPAD]
    const int* __restrict__ icomp,          // MODE1: [HID*NBR][NNZ]
    uint64_t* __restrict__ outm)            // [HID][TPAD]
{
    const int tid  = threadIdx.x;
    const int lane = tid & 63;
    const int wid  = __builtin_amdgcn_readfirstlane(tid >> 6); // 0..7, uniform
    const int h    = blockIdx.x;
    const int r    = h * NBR + wid;         // this wave's row (uniform)

    __shared__ uint2 ent[(MODE == 0) ? (NBR * NNZ) : 1]; // MODE0: (w,idx)
    __shared__ float wl[(MODE == 1) ? (NBR * NNZ) : 1];  // MODE1: w only
    __shared__ float red[2][NBR * CH * 64]; // double-buffered partial sums

    inm = (const uint64_t*)__builtin_assume_aligned(inm, 64);

    // ---- gather masked weights into LDS (ballot compaction) ----
    const unsigned char* m8  = (const unsigned char*)maskp;
    const int*           m32 = (const int*)maskp;
    {
        const int base = wid * NNZ;
        int cnt = 0;
        for (int c = 0; c * 64 < DIN; ++c) {
            const int i = c * 64 + lane;
            int   mv = 0;
            float wv = 0.f;
            if (i < DIN) {
                mv = m8[(size_t)r * DIN + i];
                wv = w[(size_t)r * DIN + i];
            }
            const unsigned long long bal = __ballot(mv != 0);
            const int pos = __popcll(bal & ((1ull << lane) - 1ull));
            if (mv && cnt + pos < NNZ) {
                if constexpr (MODE == 0)
                    ent[base + cnt + pos] =
                        make_uint2(__float_as_uint(wv), (unsigned)i);
                else
                    wl[base + cnt + pos] = wv;
            }
            cnt += __popcll(bal);
        }
        if (cnt != NNZ) {   // masks are int32 after all
            cnt = 0;
            for (int c = 0; c * 64 < DIN; ++c) {
                const int i = c * 64 + lane;
                int   mv = 0;
                float wv = 0.f;
                if (i < DIN) {
                    mv = m32[(size_t)r * DIN + i];
                    wv = w[(size_t)r * DIN + i];
                }
                const unsigned long long bal = __ballot(mv != 0);
                const int pos = __popcll(bal & ((1ull << lane) - 1ull));
                if (mv && cnt + pos < NNZ) {
                    if constexpr (MODE == 0)
                        ent[base + cnt + pos] =
                            make_uint2(__float_as_uint(wv), (unsigned)i);
                    else
                        wl[base + cnt + pos] = wv;
                }
                cnt += __popcll(bal);
            }
        }
    }
    __syncthreads();

    const float be = 1.f / (1.f + expf(-tau_n[r]));
    const float om = 1.f - be;
    const float bb = bias[r];
    const float al  = 1.f / (1.f + expf(-tau_m[h]));
    const float oma = 1.f - al;

    float d = 0.f, mem = 0.f, spkprev = 0.f;
    const int base = wid * NNZ;

    for (int tc = 0; tc < NCHUNK; ++tc) {
        const int t0  = tc * CH;
        const int buf = tc & 1;
        float a[CH];
#pragma unroll
        for (int k = 0; k < CH; ++k) a[k] = 0.f;

        if constexpr (MODE == 1) {
            const int* __restrict__ icp = icomp + (size_t)r * NNZ;
            static_assert(NNZ % 8 == 0, "NNZ multiple of 8");
#pragma unroll 2
            for (int jb = 0; jb < NNZ / 8; ++jb) {
                const i32x8 ix8 = *(const ci32x8*)(icp + jb * 8);      // SGPR
                const f32x8 wv8 = *(const f32x8*)(&wl[base + jb * 8]); // VGPR
#pragma unroll
                for (int jj = 0; jj < 8; ++jj) {
                    const u64x8 m =
                        *(const cu64x8*)(inm + (size_t)ix8[jj] * TPAD + t0);
                    const float wv = wv8[jj];
#pragma unroll
                    for (int k = 0; k < CH; ++k) {
                        float s;
                        asm("v_cndmask_b32 %0, 0, %1, %2"
                            : "=v"(s) : "v"(wv), "s"(m[k]));
                        a[k] += s;
                    }
                }
            }
        } else {
            const float* xb = xin + (size_t)t0 * DIN * 64;
#pragma unroll 3
            for (int j = 0; j < NNZ; ++j) {
                const uint2 e  = ent[base + j];
                const int   ix = __builtin_amdgcn_readfirstlane((int)e.y);
                const float wv = __uint_as_float(e.x);
#pragma unroll
                for (int k = 0; k < CH; ++k)
                    a[k] += wv * xb[((size_t)k * DIN + ix) * 64 + lane];
            }
        }

        // branch decay (sequential within chunk), stash per-row d
#pragma unroll
        for (int k = 0; k < CH; ++k) {
            d = be * d + om * (a[k] + bb);
            red[buf][(wid * CH + k) * 64 + lane] = d;
        }
        // one barrier per chunk: waves 1..7 run chunk tc+1 into buf^1 while
        // wave 0 reduces buf; buf is rewritten only after the NEXT barrier.
        __syncthreads();

        if (wid == 0) {
#pragma unroll
            for (int k = 0; k < CH; ++k) {
                // EXACT old pair order: ((d0+d1)+(d2+d3))+(d4+d5))+(d6+d7)
                const float r0 = red[buf][(0 * CH + k) * 64 + lane];
                const float r1 = red[buf][(1 * CH + k) * 64 + lane];
                const float r2 = red[buf][(2 * CH + k) * 64 + lane];
                const float r3 = red[buf][(3 * CH + k) * 64 + lane];
                const float r4 = red[buf][(4 * CH + k) * 64 + lane];
                const float r5 = red[buf][(5 * CH + k) * 64 + lane];
                const float r6 = red[buf][(6 * CH + k) * 64 + lane];
                const float r7 = red[buf][(7 * CH + k) * 64 + lane];
                const float p01 = r0 + r1, p23 = r2 + r3;
                const float p45 = r4 + r5, p67 = r6 + r7;
                const float l = ((p01 + p23) + p45) + p67;
                if (t0 + k < TT) {
                    mem = al * mem + oma * l - spkprev;   // VTH = 1.0
                    spkprev = (mem > 1.0f) ? 1.f : 0.f;
                    const unsigned long long bal = __ballot(mem > 1.0f);
                    if (lane == 0) outm[(size_t)h * TPAD + (t0 + k)] = bal;
                }
            }
        }
    }
}

// Y[t][o][b] = wr[o] . s3(t,:,b); 4 waves split the i range (reorder safe:
// readout is linear, no thresholds downstream). wid goes through
// readfirstlane so LLVM knows the mask addresses are uniform; masks are read
// through AS(4) pointers -> scalar s_load, no marshalling.
__global__ __launch_bounds__(256) void k_ry(const float* __restrict__ wr,
                                            const uint64_t* __restrict__ s3m,
                                            float* __restrict__ Y) {
    const int lane  = threadIdx.x & 63;
    const int wid   = __builtin_amdgcn_readfirstlane(threadIdx.x >> 6); // 0..3
    const int o  = blockIdx.x / NCHUNK;
    const int t0 = (blockIdx.x % NCHUNK) * CH;
    s3m = (const uint64_t*)__builtin_assume_aligned(s3m, 64);
    const float* wrow = wr + (size_t)o * HID;
    __shared__ float red[4 * CH * 64];
    float acc[CH];
#pragma unroll
    for (int k = 0; k < CH; ++k) acc[k] = 0.f;
#pragma unroll 4
    for (int ii = 0; ii < HID / 4; ++ii) {
        const int i = wid * (HID / 4) + ii;
        const float wv = wrow[i];
        const u64x8 m = *(const cu64x8*)(s3m + (size_t)i * TPAD + t0);
#pragma unroll
        for (int k = 0; k < CH; ++k) {
            float s;
            asm("v_cndmask_b32 %0, 0, %1, %2" : "=v"(s) : "v"(wv), "s"(m[k]));
            acc[k] += s;
        }
    }
#pragma unroll
    for (int k = 0; k < CH; ++k)
        red[(wid * CH + k) * 64 + lane] = acc[k];
    __syncthreads();
    if (wid == 0) {
#pragma unroll
        for (int k = 0; k < CH; ++k) {
            if (t0 + k >= TT) break;
            const float v = ((red[(0 * CH + k) * 64 + lane]
                            + red[(1 * CH + k) * 64 + lane])
                            + red[(2 * CH + k) * 64 + lane])
                            + red[(3 * CH + k) * 64 + lane];
            Y[((size_t)(t0 + k) * OUTN + o) * 64 + lane] = v;
        }
    }
}

// acc[o][b] = sum_t (Y + br[o]) * (1 - ar^(150-t))   (closed-form mr scan)
__global__ void k_racc(const float* __restrict__ Y,
                       const float* __restrict__ br,
                       const float* __restrict__ tau_mr,
                       float* __restrict__ ACC) {
    const int o = blockIdx.x, lane = threadIdx.x;
    const float ar  = 1.f / (1.f + expf(-tau_mr[o]));
    const float bro = br[o];
    float acc = 0.f, q = ar;
    for (int t = TT - 1; t >= 0; --t) {
        const float y = Y[((size_t)t * OUTN + o) * 64 + lane] + bro;
        acc += y * (1.f - q);
        q *= ar;
    }
    ACC[o * 64 + lane] = acc;
}

__global__ void k_smax(const float* __restrict__ ACC, float* __restrict__ out) {
    const int b = threadIdx.x;   // 64 threads
    float v[OUTN];
    float mx = -3.4e38f;
    for (int o = 0; o < OUTN; ++o) {
        v[o] = ACC[o * 64 + b] / (float)TT;
        mx = fmaxf(mx, v[o]);
    }
    float sum = 0.f;
    for (int o = 0; o < OUTN; ++o) sum += expf(v[o] - mx);
    const float lse = mx + logf(sum);
    for (int o = 0; o < OUTN; ++o) out[b * OUTN + o] = v[o] - lse;
}

extern "C" void kernel_launch(void* const* d_in, const int* in_sizes, int n_in,
                              void* d_out, int out_size, void* d_ws,
                              size_t ws_size, hipStream_t stream) {
    (void)in_sizes; (void)n_in; (void)out_size; (void)ws_size;
    const float* x   = (const float*)d_in[0];
    const float* w1  = (const float*)d_in[1];
    const float* b1  = (const float*)d_in[2];
    const float* tm1 = (const float*)d_in[3];
    const float* tn1 = (const float*)d_in[4];
    const float* w2  = (const float*)d_in[5];
    const float* b2  = (const float*)d_in[6];
    const float* tm2 = (const float*)d_in[7];
    const float* tn2 = (const float*)d_in[8];
    const float* w3  = (const float*)d_in[9];
    const float* b3  = (const float*)d_in[10];
    const float* tm3 = (const float*)d_in[11];
    const float* tn3 = (const float*)d_in[12];
    const float* wr  = (const float*)d_in[13];
    const float* br  = (const float*)d_in[14];
    const float* tmr = (const float*)d_in[15];
    const void*  m1  = d_in[16];
    const void*  m2  = d_in[17];
    const void*  m3  = d_in[18];
    float* out = (float*)d_out;

    char* ws = (char*)d_ws;
    float*    xT  = (float*)(ws + XT_OFF);
    uint64_t* s1m = (uint64_t*)(ws + S1_OFF);
    uint64_t* s2m = (uint64_t*)(ws + S2_OFF);
    uint64_t* s3m = (uint64_t*)(ws + S3_OFF);
    float*    Y   = (float*)(ws + Y_OFF);
    float*    ACC = (float*)(ws + ACC_OFF);
    int*      ic2 = (int*)(ws + IC2_OFF);
    int*      ic3 = (int*)(ws + IC3_OFF);

    k_tx<<<TT, 256, 0, stream>>>(x, xT);
    k_cmp<<<HID, 512, 0, stream>>>(m2, ic2);
    k_cmp<<<HID, 512, 0, stream>>>(m3, ic3);
    k_layer<INSZ, 15, 0><<<HID, 512, 0, stream>>>(
        w1, m1, b1, tm1, tn1, xT, nullptr, nullptr, s1m);
    k_layer<HID, NNZC, 1><<<HID, 512, 0, stream>>>(
        w2, m2, b2, tm2, tn2, nullptr, s1m, ic2, s2m);
    k_layer<HID, NNZC, 1><<<HID, 512, 0, stream>>>(
        w3, m3, b3, tm3, tn3, nullptr, s2m, ic3, s3m);
    k_ry<<<OUTN * NCHUNK, 256, 0, stream>>>(wr, s3m, Y);
    k_racc<<<OUTN, 64, 0, stream>>>(Y, br, tmr, ACC);
    k_smax<<<1, 64, 0, stream>>>(ACC, out);
}